// Round 13
// baseline (351.299 us; speedup 1.0000x reference)
//
#include <hip/hip_runtime.h>
#include <hip/hip_bf16.h>

#define B_ 4
#define N_ 16384
#define HID_ 512
#define H_ 8
#define M_ 32
#define D_ 64
#define HM_ 256

typedef __hip_bfloat16 bf16;
typedef __bf16 bf16x8 __attribute__((ext_vector_type(8)));
typedef float f32x4 __attribute__((ext_vector_type(4)));

__device__ __forceinline__ void gl_lds16(const bf16* g, bf16* l) {
    __builtin_amdgcn_global_load_lds(
        (const __attribute__((address_space(1))) void*)g,
        (__attribute__((address_space(3))) void*)l, 16, 0, 0);
}

// XCD-aware bijective block remap (requires nwg % 8 == 0)
__device__ __forceinline__ int xcd_swz(int lin, int nwg) {
    return (lin & 7) * (nwg >> 3) + (lin >> 3);
}

// ---- linear stage: 128x64 bf16 tile -> LDS (4 gl_lds/thread, 256 thr) — k6 core (frozen)
__device__ __forceinline__ void stage_tile_lin(const bf16* __restrict__ G, long long r0,
        int kk, int ld, bf16* lds, int t) {
    const int l = t & 63, w = t >> 6;
    const int srow = l >> 3;
    const int skel = (l & 7) * 8;
#pragma unroll
    for (int j = 0; j < 4; ++j) {
        int q = j * 4 + w;
        gl_lds16(G + (r0 + q * 8 + srow) * (long long)ld + kk + skel, lds + q * 512);
    }
}

// ---- T2 swizzled stages for 512-thread k12: LDS row r slot s holds global block s^(r&7)
__device__ __forceinline__ void stage_a_sw(const bf16* __restrict__ G, long long r0,
        int kk, int ld, bf16* lds, int t) {      // 256x64 tile, 4 gl_lds/thread
    const int l = t & 63, w = t >> 6;            // w 0..7
    const int srow = l >> 3;
    const int skel = ((l & 7) ^ srow) * 8;
#pragma unroll
    for (int j = 0; j < 4; ++j) {
        int q = j * 8 + w;                       // 0..31 (8-row groups)
        gl_lds16(G + (r0 + q * 8 + srow) * (long long)ld + kk + skel, lds + q * 512);
    }
}
__device__ __forceinline__ void stage_b_sw(const bf16* __restrict__ G, long long r0,
        int kk, int ld, bf16* lds, int t) {      // 128x64 tile, 2 gl_lds/thread
    const int l = t & 63, w = t >> 6;
    const int srow = l >> 3;
    const int skel = ((l & 7) ^ srow) * 8;
#pragma unroll
    for (int j = 0; j < 2; ++j) {
        int q = j * 8 + w;                       // 0..15
        gl_lds16(G + (r0 + q * 8 + srow) * (long long)ld + kk + skel, lds + q * 512);
    }
}

// ---- one 64-K-step of MFMA on linear LDS tiles (k6 core, frozen)
__device__ __forceinline__ void mfma_half(const bf16* As, const bf16* Bs,
        int l, int wm, int wn, f32x4 acc[4][4]) {
#pragma unroll
    for (int ks = 0; ks < 64; ks += 32) {
        bf16x8 af[4], bfr[4];
#pragma unroll
        for (int mf = 0; mf < 4; ++mf)
            af[mf] = *(const bf16x8*)(As + (wm * 64 + mf * 16 + (l & 15)) * 64 + ks + (l >> 4) * 8);
#pragma unroll
        for (int nf = 0; nf < 4; ++nf)
            bfr[nf] = *(const bf16x8*)(Bs + (wn * 64 + nf * 16 + (l & 15)) * 64 + ks + (l >> 4) * 8);
#pragma unroll
        for (int mf = 0; mf < 4; ++mf)
#pragma unroll
            for (int nf = 0; nf < 4; ++nf)
                acc[mf][nf] = __builtin_amdgcn_mfma_f32_16x16x32_bf16(af[mf], bfr[nf], acc[mf][nf], 0, 0, 0);
    }
}

// ---- one 64-K-step of MFMA on XOR-swizzled LDS tiles (wm may span 0..3 for 256-row A)
__device__ __forceinline__ void mfma_half_sw(const bf16* As, const bf16* Bs,
        int l, int wm, int wn, f32x4 acc[4][4]) {
    const int l15 = l & 15;
    const int xsw = (l & 7) * 8;
    const int kq = (l >> 4) * 8;
#pragma unroll
    for (int ks = 0; ks < 64; ks += 32) {
        const int ko = (ks + kq) ^ xsw;
        bf16x8 af[4], bfr[4];
#pragma unroll
        for (int mf = 0; mf < 4; ++mf)
            af[mf] = *(const bf16x8*)(As + (wm * 64 + mf * 16 + l15) * 64 + ko);
#pragma unroll
        for (int nf = 0; nf < 4; ++nf)
            bfr[nf] = *(const bf16x8*)(Bs + (wn * 64 + nf * 16 + l15) * 64 + ko);
#pragma unroll
        for (int mf = 0; mf < 4; ++mf)
#pragma unroll
            for (int nf = 0; nf < 4; ++nf)
                acc[mf][nf] = __builtin_amdgcn_mfma_f32_16x16x32_bf16(af[mf], bfr[nf], acc[mf][nf], 0, 0, 0);
    }
}

// ---- r3 MFMA GEMM core (single-buffer): used by k6 (frozen)
__device__ __forceinline__ void mfma_core(
        const bf16* __restrict__ Ag, const bf16* __restrict__ Bg,
        long long arow0, int bcol0, int lda, int ldb, int kiters,
        bf16* As, bf16* Bs, f32x4 acc[4][4]) {
    const int t = threadIdx.x;
    const int l = t & 63, w = t >> 6;
    const int wm = w >> 1, wn = w & 1;
    for (int kt = 0; kt < kiters; ++kt) {
        const int kk = kt * 64;
        stage_tile_lin(Ag, arow0, kk, lda, As, t);
        stage_tile_lin(Bg, bcol0, kk, ldb, Bs, t);
        __syncthreads();
        mfma_half(As, Bs, l, wm, wn, acc);
        __syncthreads();
    }
}

// ---- T2+T3+T4 core, 512 threads, 256x128 tile: counted vmcnt keeps the kt+1
// prefetch (6 loads/thread) in flight across the barrier.
template<int NT>
__device__ __forceinline__ void gemm_cnt256(
        const bf16* __restrict__ Ag, const bf16* __restrict__ Bg,
        long long arow0, int bcol0, int lda, int ldb,
        bf16 (*As)[16384], bf16 (*Bs)[8192], f32x4 acc[4][4]) {
    const int t = threadIdx.x;
    const int l = t & 63, w = t >> 6;
    const int wm = w >> 1, wn = w & 1;
    stage_a_sw(Ag, arow0, 0, lda, As[0], t);
    stage_b_sw(Bg, bcol0, 0, ldb, Bs[0], t);
#pragma unroll
    for (int kt = 0; kt < NT; ++kt) {
        const int cur = kt & 1;
        if (kt + 1 < NT) {
            stage_a_sw(Ag, arow0, (kt + 1) * 64, lda, As[cur ^ 1], t);
            stage_b_sw(Bg, bcol0, (kt + 1) * 64, ldb, Bs[cur ^ 1], t);
            asm volatile("s_waitcnt vmcnt(6)" ::: "memory");   // tile kt done; kt+1 flying
        } else {
            asm volatile("s_waitcnt vmcnt(0)" ::: "memory");
        }
        __builtin_amdgcn_s_barrier();
        mfma_half_sw(As[cur], Bs[cur], l, wm, wn, acc);
        __builtin_amdgcn_s_barrier();
    }
}

// ---------------- cast f32 -> bf16, 4 elems/thread
__global__ __launch_bounds__(256) void k_cast4(const float* __restrict__ s,
        ushort* __restrict__ d) {
    long long i = (long long)blockIdx.x * 256 + threadIdx.x;
    float4 v = reinterpret_cast<const float4*>(s)[i];
    ushort4 o;
    bf16 a0 = __float2bfloat16(v.x), a1 = __float2bfloat16(v.y);
    bf16 a2 = __float2bfloat16(v.z), a3 = __float2bfloat16(v.w);
    o.x = *(ushort*)&a0; o.y = *(ushort*)&a1; o.z = *(ushort*)&a2; o.w = *(ushort*)&a3;
    reinterpret_cast<ushort4*>(d)[i] = o;
}

// ---------------- wf_f32[o][k] = sum_m mix1_w[o, h*32+m] * wtq[h,m,d], k=h*64+d
__global__ __launch_bounds__(256) void k_wfused(const float* __restrict__ mix1,
        const float* __restrict__ wtq, float* __restrict__ wf) {
    const int idx = blockIdx.x * 256 + threadIdx.x;
    const int o = idx >> 9, k = idx & 511;
    const int h = k >> 6, dd = k & 63;
    float s = 0.f;
#pragma unroll
    for (int m = 0; m < 32; ++m)
        s += mix1[(long long)o * 256 + h * 32 + m] * wtq[((long long)h * 32 + m) * 64 + dd];
    wf[(long long)o * 512 + k] = s;
}

// ---------------- Wsc rows 512..767 of wv_sc + score bias + v-bias copy
__global__ __launch_bounds__(256) void k_wsc(const float* __restrict__ wf,
        const float* __restrict__ wkv, const float* __restrict__ bkv,
        const float* __restrict__ alpha1, bf16* __restrict__ wv_sc,
        float* __restrict__ bias768) {
    __shared__ float wfrow[512];
    __shared__ float red[256];
    const int o = blockIdx.x, t = threadIdx.x;
    wfrow[t] = wf[(long long)o * 512 + t];
    wfrow[t + 256] = wf[(long long)o * 512 + 256 + t];
    __syncthreads();
    const float al = alpha1[o >> 5];
    float a0 = 0.f, a1 = 0.f;
    for (int c = 0; c < 512; ++c) {
        float wv = wfrow[c];
        a0 += wv * wkv[(long long)c * 512 + t];
        a1 += wv * wkv[(long long)c * 512 + t + 256];
    }
    wv_sc[(long long)(512 + o) * 512 + t] = __float2bfloat16(a0 * al);
    wv_sc[(long long)(512 + o) * 512 + t + 256] = __float2bfloat16(a1 * al);
    float p = wfrow[t] * bkv[t] + wfrow[t + 256] * bkv[t + 256];
    red[t] = p; __syncthreads();
    for (int s = 128; s >= 1; s >>= 1) {
        if (t < s) red[t] += red[t + s];
        __syncthreads();
    }
    if (t == 0) bias768[512 + o] = red[0] * al;
    if (t < 2) bias768[o * 2 + t] = bkv[512 + o * 2 + t];   // v-bias
}

// ---------------- K12: [xv | scores] = xb @ wv_sc^T + bias768; 512 thr, 256x128 tile,
// counted-vmcnt 2-phase + T2 swizzle; score blocks: in-register m-group softmax.
__global__ __launch_bounds__(512) void k12_mfma(const bf16* __restrict__ xb,
        const bf16* __restrict__ wv_sc, const float* __restrict__ bias768,
        bf16* __restrict__ xv, float* __restrict__ swout,
        bf16* __restrict__ sw_bt, float* __restrict__ part) {
    __shared__ __align__(16) bf16 As[2][16384];
    __shared__ __align__(16) bf16 Bs[2][8192];
    f32x4 acc[4][4];
#pragma unroll
    for (int i = 0; i < 4; ++i)
#pragma unroll
        for (int j = 0; j < 4; ++j) acc[i][j] = (f32x4)(0.0f);
    const int wg = xcd_swz(blockIdx.y * 6 + blockIdx.x, 1536);
    const int bx = wg % 6, by = wg / 6;
    const long long arow0 = (long long)by * 256;
    const int bcol0 = bx * 128;
    gemm_cnt256<8>(xb, wv_sc, arow0, bcol0, 512, 512, As, Bs, acc);

    const int t = threadIdx.x;
    const int l = t & 63, w = t >> 6, wm = w >> 1, wn = w & 1;   // wm 0..3, wn 0..1
    const int l15 = l & 15, lq = l >> 4;
    // add bias
#pragma unroll
    for (int nf = 0; nf < 4; ++nf) {
        float bv = bias768[bcol0 + wn * 64 + nf * 16 + l15];
#pragma unroll
        for (int mf = 0; mf < 4; ++mf)
#pragma unroll
            for (int r = 0; r < 4; ++r) acc[mf][nf][r] += bv;
    }

    if (bcol0 >= 512) {
        // ---- in-register softmax over each m-group (32 cols = nf pair x 16 lanes)
#pragma unroll
        for (int mf = 0; mf < 4; ++mf)
#pragma unroll
            for (int r = 0; r < 4; ++r)
#pragma unroll
                for (int g = 0; g < 2; ++g) {
                    float v0 = acc[mf][2 * g][r], v1 = acc[mf][2 * g + 1][r];
                    float mx = fmaxf(v0, v1);
#pragma unroll
                    for (int mk = 1; mk <= 8; mk <<= 1) mx = fmaxf(mx, __shfl_xor(mx, mk));
                    float e0 = __expf(v0 - mx), e1 = __expf(v1 - mx);
                    float s = e0 + e1;
#pragma unroll
                    for (int mk = 1; mk <= 8; mk <<= 1) s += __shfl_xor(s, mk);
                    float ri = 1.f / s;
                    acc[mf][2 * g][r] = e0 * ri;
                    acc[mf][2 * g + 1][r] = e1 * ri;
                }
        // ---- per-column partial sums (for swsum): 4 wm-waves per column
        {
            float* cpart = (float*)&As[0][0];   // 512 floats
#pragma unroll
            for (int nf = 0; nf < 4; ++nf) {
                float ps = 0.f;
#pragma unroll
                for (int mf = 0; mf < 4; ++mf)
#pragma unroll
                    for (int r = 0; r < 4; ++r) ps += acc[mf][nf][r];
                ps += __shfl_xor(ps, 16);
                ps += __shfl_xor(ps, 32);
                if (lq == 0) cpart[wm * 128 + wn * 64 + nf * 16 + l15] = ps;
            }
            __syncthreads();
            if (t < 128)
                part[(long long)by * 256 + (bcol0 - 512) + t]
                    = cpart[t] + cpart[128 + t] + cpart[256 + t] + cpart[384 + t];
        }
        // ---- direct register stores
        const int b = (int)(arow0 >> 14);
        const int nbase = (int)(arow0 & 16383) + wm * 64;
#pragma unroll
        for (int mf = 0; mf < 4; ++mf) {
            long long rowb = arow0 + wm * 64 + mf * 16 + lq * 4;
#pragma unroll
            for (int nf = 0; nf < 4; ++nf) {
                int cglob = (bcol0 - 512) + wn * 64 + nf * 16 + l15;
                float4 v = {acc[mf][nf][0], acc[mf][nf][1], acc[mf][nf][2], acc[mf][nf][3]};
                *reinterpret_cast<float4*>(swout + ((long long)b * HM_ + cglob) * N_
                                           + nbase + mf * 16 + lq * 4) = v;
#pragma unroll
                for (int r = 0; r < 4; ++r)
                    sw_bt[(rowb + r) * 256 + cglob] = __float2bfloat16(acc[mf][nf][r]);
            }
        }
    } else {
        // ---- xv path: direct scalar bf16 stores
#pragma unroll
        for (int mf = 0; mf < 4; ++mf) {
            long long rowb = arow0 + wm * 64 + mf * 16 + lq * 4;
#pragma unroll
            for (int nf = 0; nf < 4; ++nf) {
                int col = bcol0 + wn * 64 + nf * 16 + l15;
#pragma unroll
                for (int r = 0; r < 4; ++r)
                    xv[(rowb + r) * 512 + col] = __float2bfloat16(acc[mf][nf][r]);
            }
        }
    }
}

// ---------------- K3: register-tiled outer-product: tok_part[bh][chunk][m][d]
__global__ __launch_bounds__(256) void k3_tok(const bf16* __restrict__ sw_bt,
        const bf16* __restrict__ xv, float* __restrict__ tok_part) {
    __shared__ __align__(16) float smem[17408];
    float (*swsT)[36] = reinterpret_cast<float(*)[36]>(smem);
    bf16* xvs = reinterpret_cast<bf16*>(smem + 9216);
    const int t = threadIdx.x;
    const int chunk = blockIdx.x;
    const int bh = blockIdx.y;
    const int n0 = chunk * 256;
    const int b = bh >> 3, h = bh & 7;
    // stage sw (bf16 [row][c]) transposed to [nl][m]
    {
        const long long base = ((long long)(b * N_ + n0 + t)) * 256 + h * 32;
        const uint4* sp = reinterpret_cast<const uint4*>(sw_bt + base);
        uint4 qs[4] = {sp[0], sp[1], sp[2], sp[3]};
        const uint* qu = reinterpret_cast<const uint*>(qs);
#pragma unroll
        for (int j = 0; j < 16; ++j) {
            uint u = qu[j];
            swsT[t][2 * j] = __uint_as_float(u << 16);
            swsT[t][2 * j + 1] = __uint_as_float(u & 0xffff0000u);
        }
    }
    {
        const uint* xg = reinterpret_cast<const uint*>(xv + ((long long)b * N_ + n0) * 512 + h * 64);
        uint* xls = reinterpret_cast<uint*>(xvs);
#pragma unroll
        for (int p = 0; p < 32; ++p) {
            int idx = p * 256 + t;
            int nl = idx >> 5, prt = idx & 31;
            xls[nl * 32 + prt] = xg[(long long)nl * 256 + prt];
        }
    }
    __syncthreads();
    const int l = t & 63, w = t >> 6;
    const int nlh = l >> 5, mtile = (l >> 3) & 3, dtile = l & 7;
    const int m0 = mtile * 8, d0 = dtile * 8;
    float acc[8][8] = {};
    const int wbase = w * 64;
    for (int i = 0; i < 32; ++i) {
        int nl = wbase + i * 2 + nlh;
        float4 s0 = *reinterpret_cast<const float4*>(&swsT[nl][m0]);
        float4 s1 = *reinterpret_cast<const float4*>(&swsT[nl][m0 + 4]);
        uint4 xi = *reinterpret_cast<const uint4*>(&xvs[nl * 64 + d0]);
        float xvf[8];
        xvf[0] = __uint_as_float(xi.x << 16); xvf[1] = __uint_as_float(xi.x & 0xffff0000u);
        xvf[2] = __uint_as_float(xi.y << 16); xvf[3] = __uint_as_float(xi.y & 0xffff0000u);
        xvf[4] = __uint_as_float(xi.z << 16); xvf[5] = __uint_as_float(xi.z & 0xffff0000u);
        xvf[6] = __uint_as_float(xi.w << 16); xvf[7] = __uint_as_float(xi.w & 0xffff0000u);
        float sm[8] = {s0.x, s0.y, s0.z, s0.w, s1.x, s1.y, s1.z, s1.w};
#pragma unroll
        for (int mi = 0; mi < 8; ++mi)
#pragma unroll
            for (int di = 0; di < 8; ++di)
                acc[mi][di] += sm[mi] * xvf[di];
    }
    __syncthreads();
    float* red = smem;
    float* rb = red + (w * 2 + nlh) * 2048;
#pragma unroll
    for (int mi = 0; mi < 8; ++mi) {
        float4 lo = {acc[mi][0], acc[mi][1], acc[mi][2], acc[mi][3]};
        float4 hi = {acc[mi][4], acc[mi][5], acc[mi][6], acc[mi][7]};
        *reinterpret_cast<float4*>(&rb[(m0 + mi) * 64 + d0]) = lo;
        *reinterpret_cast<float4*>(&rb[(m0 + mi) * 64 + d0 + 4]) = hi;
    }
    __syncthreads();
#pragma unroll
    for (int pp = 0; pp < 2; ++pp) {
        int idx4 = pp * 1024 + t * 4;
        float4 s = {0.f, 0.f, 0.f, 0.f};
#pragma unroll
        for (int r = 0; r < 8; ++r) {
            float4 v = *reinterpret_cast<const float4*>(&red[r * 2048 + idx4]);
            s.x += v.x; s.y += v.y; s.z += v.z; s.w += v.w;
        }
        *reinterpret_cast<float4*>(&tok_part[((long long)bh * 64 + chunk) * 2048 + idx4]) = s;
    }
}

// ---------------- K4a: sum chunks, swsum from partials (64 blocks/b), LN -> tok_ln
__global__ __launch_bounds__(64) void k4a_ln(const float* __restrict__ tok_part,
        const float* __restrict__ part, const float* __restrict__ ln_w,
        const float* __restrict__ ln_b, float* __restrict__ tok_ln) {
    const int bid = blockIdx.x;
    const int bh = bid >> 5, m = bid & 31;
    const int d = threadIdx.x;
    float s = 0.f;
    for (int ch = 0; ch < 64; ++ch)
        s += tok_part[(((long long)bh * 64 + ch) * 32 + m) * 64 + d];
    const int b = bid >> 8, c = bid & 255;
    float ssum = part[((long long)(b * 64 + d)) * 256 + c];
#pragma unroll
    for (int mk = 32; mk >= 1; mk >>= 1) ssum += __shfl_xor(ssum, mk, 64);
    float tokv = s / (ssum + 1e-5f);
    float mu = tokv;
#pragma unroll
    for (int mk = 32; mk >= 1; mk >>= 1) mu += __shfl_xor(mu, mk, 64);
    mu *= (1.f / 64.f);
    float df = tokv - mu;
    float var = df * df;
#pragma unroll
    for (int mk = 32; mk >= 1; mk >>= 1) var += __shfl_xor(var, mk, 64);
    var *= (1.f / 64.f);
    float y = df * rsqrtf(var + 1e-5f) * ln_w[d] + ln_b[d];
    const int bb = bh >> 3, h = bh & 7;
    tok_ln[((long long)bb * 32 + m) * 512 + h * 64 + d] = y;
}

// ---------------- wqkvT[k][j] = wqkv[j][k]
__global__ __launch_bounds__(256) void k_wqT(const float* __restrict__ wq,
        float* __restrict__ wqT) {
    __shared__ float tile[32][33];
    const int k0 = blockIdx.x * 32;
    const int j0 = blockIdx.y * 32;
    const int tx = threadIdx.x & 31, ty = threadIdx.x >> 5;
#pragma unroll
    for (int r = 0; r < 32; r += 8)
        tile[ty + r][tx] = wq[(long long)(j0 + ty + r) * 512 + k0 + tx];
    __syncthreads();
#pragma unroll
    for (int r = 0; r < 32; r += 8)
        wqT[(long long)(k0 + ty + r) * 1536 + j0 + tx] = tile[tx][ty + r];
}

// ---------------- K4b: qkv = tok_ln @ wqkv^T via transposed weights
__global__ __launch_bounds__(256) void k4b_qkv(const float* __restrict__ tok_ln,
        const float* __restrict__ wqT, float* __restrict__ qkv) {
    const int j = (blockIdx.x % 6) * 256 + threadIdx.x;
    const int r0 = (blockIdx.x / 6) * 4;
    float a0 = 0, a1 = 0, a2 = 0, a3 = 0;
    for (int k = 0; k < 512; ++k) {
        float wv = wqT[(long long)k * 1536 + j];
        a0 += tok_ln[(r0 + 0) * 512 + k] * wv;
        a1 += tok_ln[(r0 + 1) * 512 + k] * wv;
        a2 += tok_ln[(r0 + 2) * 512 + k] * wv;
        a3 += tok_ln[(r0 + 3) * 512 + k] * wv;
    }
    qkv[(long long)(r0 + 0) * 1536 + j] = a0;
    qkv[(long long)(r0 + 1) * 1536 + j] = a1;
    qkv[(long long)(r0 + 2) * 1536 + j] = a2;
    qkv[(long long)(r0 + 3) * 1536 + j] = a3;
}

// ---------------- K4c: inner MHA (M=32) per (b,h)
__global__ __launch_bounds__(256) void k4c_attn(const float* __restrict__ qkv,
        float* __restrict__ out_tok, float* __restrict__ attn_out) {
    __shared__ float qsT[64][33], ksT[64][33], vsT[64][33];
    __shared__ float att[32][33];
    __shared__ float rinv[32];
    const int t = threadIdx.x;
    const int bid = blockIdx.x;
    const int b = bid >> 3, h = bid & 7;
#pragma unroll
    for (int i = 0; i < 8; ++i) {
        int idx = i * 256 + t;
        int mi = idx >> 6, dd = idx & 63;
        long long base = ((long long)b * 32 + mi) * 1536 + h * 64 + dd;
        qsT[dd][mi] = qkv[base];
        ksT[dd][mi] = qkv[base + 512];
        vsT[dd][mi] = qkv[base + 1024];
    }
    __syncthreads();
#pragma unroll
    for (int i = 0; i < 4; ++i) {
        int idx = i * 256 + t;
        int qi = idx >> 5, ki = idx & 31;
        float s = 0.f;
#pragma unroll
        for (int dd = 0; dd < 64; ++dd) s += qsT[dd][qi] * ksT[dd][ki];
        att[qi][ki] = s * 0.125f;
    }
    __syncthreads();
    if (t < 32) {
        float mx = -1e30f;
        for (int k = 0; k < 32; ++k) mx = fmaxf(mx, att[t][k]);
        float sum = 0.f;
        for (int k = 0; k < 32; ++k) { float e = __expf(att[t][k] - mx); att[t][k] = e; sum += e; }
        rinv[t] = 1.f / sum;
    }
    __syncthreads();
#pragma unroll
    for (int i = 0; i < 4; ++i) {
        int idx = i * 256 + t;
        int qi = idx >> 5, ki = idx & 31;
        float a = att[qi][ki] * rinv[qi];
        att[qi][ki] = a;
        attn_out[(long long)bid * 1024 + qi * 32 + ki] = a;
    }
    __syncthreads();
#pragma unroll
    for (int i = 0; i < 8; ++i) {
        int idx = i * 256 + t;
        int qi = idx >> 6, dd = idx & 63;
        float s = 0.f;
#pragma unroll
        for (int ki = 0; ki < 32; ++ki) s += att[qi][ki] * vsT[dd][ki];
        out_tok[((long long)bid * 32 + qi) * 64 + dd] = s;
    }
}

// ---------------- K5: W2b[b][o][c] bf16
__global__ __launch_bounds__(256) void k5_w2(const float* __restrict__ wout,
        const float* __restrict__ out_tok, bf16* __restrict__ W2) {
    const int bid = blockIdx.x;
    const int b = bid >> 9, o = bid & 511;
    const int t = threadIdx.x;
    const int h = t >> 5, m = t & 31;
    float s = 0.f;
#pragma unroll
    for (int dd = 0; dd < 64; ++dd)
        s += wout[(long long)o * 512 + h * 64 + dd]
           * out_tok[(((long long)b * 8 + h) * 32 + m) * 64 + dd];
    W2[(long long)bid * 256 + t] = __float2bfloat16(s);
}

// ---------------- K6: out = sw_bt @ W2b^T + bout
__global__ __launch_bounds__(256) void k6_mfma(const bf16* __restrict__ sw_bt,
        const bf16* __restrict__ W2, const float* __restrict__ bout,
        float* __restrict__ out) {
    __shared__ bf16 As[128 * 64], Bs[128 * 64];
    f32x4 acc[4][4];
#pragma unroll
    for (int i = 0; i < 4; ++i)
#pragma unroll
        for (int j = 0; j < 4; ++j) acc[i][j] = (f32x4)(0.0f);
    const int wg = xcd_swz((blockIdx.z * 128 + blockIdx.y) * 4 + blockIdx.x, 2048);
    const int bx = wg & 3, by = (wg >> 2) & 127, bz = wg >> 9;
    const long long arow0 = (long long)by * 128;
    const int bcol0 = bx * 128;
    mfma_core(sw_bt + (long long)bz * N_ * 256, W2 + (long long)bz * 512 * 256,
              arow0, bcol0, 256, 256, 4, As, Bs, acc);
    const int l = threadIdx.x & 63, w = threadIdx.x >> 6;
    const int wm = w >> 1, wn = w & 1;
#pragma unroll
    for (int mf = 0; mf < 4; ++mf) {
#pragma unroll
        for (int nf = 0; nf < 4; ++nf) {
            int col = bcol0 + wn * 64 + nf * 16 + (l & 15);
            float bv = bout[col];
#pragma unroll
            for (int r = 0; r < 4; ++r) {
                long long row = arow0 + wm * 64 + mf * 16 + (l >> 4) * 4 + r;
                out[((long long)bz * N_ + row) * 512 + col] = acc[mf][nf][r] + bv;
            }
        }
    }
}

// ---------------- misc outputs
__global__ void k_misc(const float* __restrict__ alpha1,
        float* __restrict__ outA, float* __restrict__ outZ) {
    int t = threadIdx.x;
    if (t < 8) outA[t] = alpha1[t];
    outZ[t] = 0.f;
}

extern "C" void kernel_launch(void* const* d_in, const int* in_sizes, int n_in,
                              void* d_out, int out_size, void* d_ws, size_t ws_size,
                              hipStream_t stream) {
    const float* x      = (const float*)d_in[0];
    const float* wkv    = (const float*)d_in[1];
    const float* bkv    = (const float*)d_in[2];
    const float* wtq    = (const float*)d_in[3];
    const float* alpha1 = (const float*)d_in[4];
    const float* mix1_w = (const float*)d_in[5];
    const float* ln1_w  = (const float*)d_in[6];
    const float* ln1_b  = (const float*)d_in[7];
    const float* wqkv   = (const float*)d_in[8];
    const float* wout   = (const float*)d_in[9];
    const float* bout   = (const float*)d_in[10];

    float* out    = (float*)d_out;
    float* swout  = out + 33554432LL;
    float* alphaO = out + 50331648LL;
    float* zerosO = out + 50331656LL;
    float* attnO  = out + 50331912LL;

    char* ws = (char*)d_ws;
    bf16*  xb        = (bf16*)(ws);                      // 64 MiB [cast -> k12]
    float* wqkvT     = (float*)(ws);                     // 3 MiB  [wqT -> k4b] (over dead xb)
    float* wf_f32    = (float*)(ws + 35651584LL);        // 512 KiB [wfused -> wsc] (over xb, dead before x-cast)
    float* part      = (float*)(ws + 67108864LL);        // 256 KiB [k12 -> k4a]
    bf16*  sw_bt     = (bf16*)(ws + 100663296LL);        // 32 MiB [k12 -> k3,k6]
    bf16*  xv        = (bf16*)(ws + 134217728LL);        // 64 MiB [k12 -> k3]
    float* tok_part  = (float*)(ws + 201326592LL);       // 16 MiB [k3 -> k4a]
    float* tok_ln    = (float*)(ws + 218107904LL);       // 256 KiB
    float* qkv       = (float*)(ws + 218370048LL);       // 768 KiB
    float* out_tok   = (float*)(ws + 219156480LL);       // 256 KiB
    bf16*  W2b       = (bf16*)(ws + 219418624LL);        // 1 MiB
    bf16*  wv_sc     = (bf16*)(ws + 220467200LL);        // 768 KiB [768][512]
    float* bias768   = (float*)(ws + 221253632LL);       // 3 KiB

    // prep: weights (wf_f32 lives inside xb region, dead before x-cast)
    k_cast4<<<256, 256, 0, stream>>>(wkv + 262144, (ushort*)wv_sc);   // v-half -> rows 0..511
    k_wfused<<<512, 256, 0, stream>>>(mix1_w, wtq, wf_f32);
    k_wsc<<<256, 256, 0, stream>>>(wf_f32, wkv, bkv, alpha1, wv_sc, bias768);
    k_cast4<<<32768, 256, 0, stream>>>(x, (ushort*)xb);
    // main pipeline
    k12_mfma<<<dim3(6, 256), 512, 0, stream>>>(xb, wv_sc, bias768, xv, swout, sw_bt, part);
    k_wqT<<<dim3(16, 48), 256, 0, stream>>>(wqkv, wqkvT);
    k3_tok<<<dim3(64, 32), 256, 0, stream>>>(sw_bt, xv, tok_part);
    k4a_ln<<<1024, 64, 0, stream>>>(tok_part, part, ln1_w, ln1_b, tok_ln);
    k4b_qkv<<<192, 256, 0, stream>>>(tok_ln, wqkvT, qkv);
    k4c_attn<<<32, 256, 0, stream>>>(qkv, out_tok, attnO);
    k5_w2<<<2048, 256, 0, stream>>>(wout, out_tok, W2b);
    k6_mfma<<<dim3(4, 128, 4), 256, 0, stream>>>(sw_bt, W2b, bout, out);
    k_misc<<<1, 256, 0, stream>>>(alpha1, alphaO, zerosO);
}

// Round 14
// 334.562 us; speedup vs baseline: 1.0500x; 1.0500x over previous
//
#include <hip/hip_runtime.h>
#include <hip/hip_bf16.h>

#define B_ 4
#define N_ 16384
#define HID_ 512
#define H_ 8
#define M_ 32
#define D_ 64
#define HM_ 256

typedef __hip_bfloat16 bf16;
typedef __bf16 bf16x8 __attribute__((ext_vector_type(8)));
typedef float f32x4 __attribute__((ext_vector_type(4)));

__device__ __forceinline__ void gl_lds16(const bf16* g, bf16* l) {
    __builtin_amdgcn_global_load_lds(
        (const __attribute__((address_space(1))) void*)g,
        (__attribute__((address_space(3))) void*)l, 16, 0, 0);
}

// XCD-aware bijective block remap (requires nwg % 8 == 0)
__device__ __forceinline__ int xcd_swz(int lin, int nwg) {
    return (lin & 7) * (nwg >> 3) + (lin >> 3);
}

// ---- T2 swizzled stage: global col-block (l&7)^srow -> linear LDS slot l&7.
// LDS row r slot s holds global block s^(r&7); read back with the same XOR.
__device__ __forceinline__ void stage_tile_sw(const bf16* __restrict__ G, long long r0,
        int kk, int ld, bf16* lds, int t) {
    const int l = t & 63, w = t >> 6;
    const int srow = l >> 3;
    const int skel = ((l & 7) ^ srow) * 8;   // pre-swizzled source col block
#pragma unroll
    for (int j = 0; j < 4; ++j) {
        int q = j * 4 + w;
        gl_lds16(G + (r0 + q * 8 + srow) * (long long)ld + kk + skel, lds + q * 512);
    }
}

// ---- one 64-K-step of MFMA on XOR-swizzled LDS tiles; T5 setprio around cluster
__device__ __forceinline__ void mfma_half_sw(const bf16* As, const bf16* Bs,
        int l, int wm, int wn, f32x4 acc[4][4]) {
    const int l15 = l & 15;
    const int xsw = (l & 7) * 8;
    const int kq = (l >> 4) * 8;
    __builtin_amdgcn_s_setprio(1);
#pragma unroll
    for (int ks = 0; ks < 64; ks += 32) {
        const int ko = (ks + kq) ^ xsw;
        bf16x8 af[4], bfr[4];
#pragma unroll
        for (int mf = 0; mf < 4; ++mf)
            af[mf] = *(const bf16x8*)(As + (wm * 64 + mf * 16 + l15) * 64 + ko);
#pragma unroll
        for (int nf = 0; nf < 4; ++nf)
            bfr[nf] = *(const bf16x8*)(Bs + (wn * 64 + nf * 16 + l15) * 64 + ko);
#pragma unroll
        for (int mf = 0; mf < 4; ++mf)
#pragma unroll
            for (int nf = 0; nf < 4; ++nf)
                acc[mf][nf] = __builtin_amdgcn_mfma_f32_16x16x32_bf16(af[mf], bfr[nf], acc[mf][nf], 0, 0, 0);
    }
    __builtin_amdgcn_s_setprio(0);
}

// ---- T2+T3+T4 2-phase core: counted vmcnt keeps the kt+1 prefetch (8 loads/thread)
// in flight across the barrier; tiles XOR-swizzled for conflict-free ds_read.
template<int NT>
__device__ __forceinline__ void gemm_cnt(
        const bf16* __restrict__ Ag, const bf16* __restrict__ Bg,
        long long arow0, int bcol0, int lda, int ldb,
        bf16 (*As)[8192], bf16 (*Bs)[8192], f32x4 acc[4][4]) {
    const int t = threadIdx.x;
    const int l = t & 63, w = t >> 6;
    const int wm = w >> 1, wn = w & 1;
    stage_tile_sw(Ag, arow0, 0, lda, As[0], t);
    stage_tile_sw(Bg, bcol0, 0, ldb, Bs[0], t);
#pragma unroll
    for (int kt = 0; kt < NT; ++kt) {
        const int cur = kt & 1;
        if (kt + 1 < NT) {
            stage_tile_sw(Ag, arow0, (kt + 1) * 64, lda, As[cur ^ 1], t);
            stage_tile_sw(Bg, bcol0, (kt + 1) * 64, ldb, Bs[cur ^ 1], t);
            asm volatile("s_waitcnt vmcnt(8)" ::: "memory");   // tile kt done; kt+1 flying
        } else {
            asm volatile("s_waitcnt vmcnt(0)" ::: "memory");
        }
        __builtin_amdgcn_s_barrier();       // staging visible to all waves
        mfma_half_sw(As[cur], Bs[cur], l, wm, wn, acc);
        __builtin_amdgcn_s_barrier();       // all reads done before buf reuse next iter
    }
}

// ---------------- cast f32 -> bf16, 4 elems/thread
__global__ __launch_bounds__(256) void k_cast4(const float* __restrict__ s,
        ushort* __restrict__ d) {
    long long i = (long long)blockIdx.x * 256 + threadIdx.x;
    float4 v = reinterpret_cast<const float4*>(s)[i];
    ushort4 o;
    bf16 a0 = __float2bfloat16(v.x), a1 = __float2bfloat16(v.y);
    bf16 a2 = __float2bfloat16(v.z), a3 = __float2bfloat16(v.w);
    o.x = *(ushort*)&a0; o.y = *(ushort*)&a1; o.z = *(ushort*)&a2; o.w = *(ushort*)&a3;
    reinterpret_cast<ushort4*>(d)[i] = o;
}

// ---------------- wf_f32[o][k] = sum_m mix1_w[o, h*32+m] * wtq[h,m,d], k=h*64+d
__global__ __launch_bounds__(256) void k_wfused(const float* __restrict__ mix1,
        const float* __restrict__ wtq, float* __restrict__ wf) {
    const int idx = blockIdx.x * 256 + threadIdx.x;
    const int o = idx >> 9, k = idx & 511;
    const int h = k >> 6, dd = k & 63;
    float s = 0.f;
#pragma unroll
    for (int m = 0; m < 32; ++m)
        s += mix1[(long long)o * 256 + h * 32 + m] * wtq[((long long)h * 32 + m) * 64 + dd];
    wf[(long long)o * 512 + k] = s;
}

// ---------------- Wsc rows 512..767 of wv_sc + score bias + v-bias copy
__global__ __launch_bounds__(256) void k_wsc(const float* __restrict__ wf,
        const float* __restrict__ wkv, const float* __restrict__ bkv,
        const float* __restrict__ alpha1, bf16* __restrict__ wv_sc,
        float* __restrict__ bias768) {
    __shared__ float wfrow[512];
    __shared__ float red[256];
    const int o = blockIdx.x, t = threadIdx.x;
    wfrow[t] = wf[(long long)o * 512 + t];
    wfrow[t + 256] = wf[(long long)o * 512 + 256 + t];
    __syncthreads();
    const float al = alpha1[o >> 5];
    float a0 = 0.f, a1 = 0.f;
    for (int c = 0; c < 512; ++c) {
        float wv = wfrow[c];
        a0 += wv * wkv[(long long)c * 512 + t];
        a1 += wv * wkv[(long long)c * 512 + t + 256];
    }
    wv_sc[(long long)(512 + o) * 512 + t] = __float2bfloat16(a0 * al);
    wv_sc[(long long)(512 + o) * 512 + t + 256] = __float2bfloat16(a1 * al);
    float p = wfrow[t] * bkv[t] + wfrow[t + 256] * bkv[t + 256];
    red[t] = p; __syncthreads();
    for (int s = 128; s >= 1; s >>= 1) {
        if (t < s) red[t] += red[t + s];
        __syncthreads();
    }
    if (t == 0) bias768[512 + o] = red[0] * al;
    if (t < 2) bias768[o * 2 + t] = bkv[512 + o * 2 + t];   // v-bias
}

// ---------------- K12: [xv | scores] = xb @ wv_sc^T + bias768; counted-vmcnt 2-phase
// with T2 swizzle; score blocks run the m-group softmax in-register; direct stores.
__global__ __launch_bounds__(256) void k12_mfma(const bf16* __restrict__ xb,
        const bf16* __restrict__ wv_sc, const float* __restrict__ bias768,
        bf16* __restrict__ xv, float* __restrict__ swout,
        bf16* __restrict__ sw_bt, float* __restrict__ part) {
    __shared__ __align__(16) bf16 As[2][8192];
    __shared__ __align__(16) bf16 Bs[2][8192];
    f32x4 acc[4][4];
#pragma unroll
    for (int i = 0; i < 4; ++i)
#pragma unroll
        for (int j = 0; j < 4; ++j) acc[i][j] = (f32x4)(0.0f);
    const int wg = xcd_swz(blockIdx.y * 6 + blockIdx.x, 3072);
    const int bx = wg % 6, by = wg / 6;
    const long long arow0 = (long long)by * 128;
    const int bcol0 = bx * 128;
    gemm_cnt<8>(xb, wv_sc, arow0, bcol0, 512, 512, As, Bs, acc);

    const int t = threadIdx.x;
    const int l = t & 63, w = t >> 6, wm = w >> 1, wn = w & 1;
    const int l15 = l & 15, lq = l >> 4;
    // add bias
#pragma unroll
    for (int nf = 0; nf < 4; ++nf) {
        float bv = bias768[bcol0 + wn * 64 + nf * 16 + l15];
#pragma unroll
        for (int mf = 0; mf < 4; ++mf)
#pragma unroll
            for (int r = 0; r < 4; ++r) acc[mf][nf][r] += bv;
    }

    if (bcol0 >= 512) {
        // ---- in-register softmax over each m-group (32 cols = nf pair x 16 lanes)
#pragma unroll
        for (int mf = 0; mf < 4; ++mf)
#pragma unroll
            for (int r = 0; r < 4; ++r)
#pragma unroll
                for (int g = 0; g < 2; ++g) {
                    float v0 = acc[mf][2 * g][r], v1 = acc[mf][2 * g + 1][r];
                    float mx = fmaxf(v0, v1);
#pragma unroll
                    for (int mk = 1; mk <= 8; mk <<= 1) mx = fmaxf(mx, __shfl_xor(mx, mk));
                    float e0 = __expf(v0 - mx), e1 = __expf(v1 - mx);
                    float s = e0 + e1;
#pragma unroll
                    for (int mk = 1; mk <= 8; mk <<= 1) s += __shfl_xor(s, mk);
                    float ri = 1.f / s;
                    acc[mf][2 * g][r] = e0 * ri;
                    acc[mf][2 * g + 1][r] = e1 * ri;
                }
        // ---- per-column partial sums (for swsum)
        {
            float* cpart = (float*)&As[0][0];   // 256 floats
#pragma unroll
            for (int nf = 0; nf < 4; ++nf) {
                float ps = 0.f;
#pragma unroll
                for (int mf = 0; mf < 4; ++mf)
#pragma unroll
                    for (int r = 0; r < 4; ++r) ps += acc[mf][nf][r];
                ps += __shfl_xor(ps, 16);
                ps += __shfl_xor(ps, 32);
                if (lq == 0) cpart[wm * 128 + wn * 64 + nf * 16 + l15] = ps;
            }
            __syncthreads();
            if (t < 128)
                part[(long long)by * 256 + (bcol0 - 512) + t] = cpart[t] + cpart[128 + t];
        }
        // ---- direct register stores
        const int b = (int)(arow0 >> 14);
        const int nbase = (int)(arow0 & 16383) + wm * 64;
#pragma unroll
        for (int mf = 0; mf < 4; ++mf) {
            long long rowb = arow0 + wm * 64 + mf * 16 + lq * 4;
#pragma unroll
            for (int nf = 0; nf < 4; ++nf) {
                int cglob = (bcol0 - 512) + wn * 64 + nf * 16 + l15;
                float4 v = {acc[mf][nf][0], acc[mf][nf][1], acc[mf][nf][2], acc[mf][nf][3]};
                *reinterpret_cast<float4*>(swout + ((long long)b * HM_ + cglob) * N_
                                           + nbase + mf * 16 + lq * 4) = v;
#pragma unroll
                for (int r = 0; r < 4; ++r)
                    sw_bt[(rowb + r) * 256 + cglob] = __float2bfloat16(acc[mf][nf][r]);
            }
        }
    } else {
        // ---- xv path: direct scalar bf16 stores
#pragma unroll
        for (int mf = 0; mf < 4; ++mf) {
            long long rowb = arow0 + wm * 64 + mf * 16 + lq * 4;
#pragma unroll
            for (int nf = 0; nf < 4; ++nf) {
                int col = bcol0 + wn * 64 + nf * 16 + l15;
#pragma unroll
                for (int r = 0; r < 4; ++r)
                    xv[(rowb + r) * 512 + col] = __float2bfloat16(acc[mf][nf][r]);
            }
        }
    }
}

// ---------------- K3: register-tiled outer-product: tok_part[bh][chunk][m][d]
__global__ __launch_bounds__(256) void k3_tok(const bf16* __restrict__ sw_bt,
        const bf16* __restrict__ xv, float* __restrict__ tok_part) {
    __shared__ __align__(16) float smem[17408];
    float (*swsT)[36] = reinterpret_cast<float(*)[36]>(smem);
    bf16* xvs = reinterpret_cast<bf16*>(smem + 9216);
    const int t = threadIdx.x;
    const int chunk = blockIdx.x;
    const int bh = blockIdx.y;
    const int n0 = chunk * 256;
    const int b = bh >> 3, h = bh & 7;
    // stage sw (bf16 [row][c]) transposed to [nl][m]
    {
        const long long base = ((long long)(b * N_ + n0 + t)) * 256 + h * 32;
        const uint4* sp = reinterpret_cast<const uint4*>(sw_bt + base);
        uint4 qs[4] = {sp[0], sp[1], sp[2], sp[3]};
        const uint* qu = reinterpret_cast<const uint*>(qs);
#pragma unroll
        for (int j = 0; j < 16; ++j) {
            uint u = qu[j];
            swsT[t][2 * j] = __uint_as_float(u << 16);
            swsT[t][2 * j + 1] = __uint_as_float(u & 0xffff0000u);
        }
    }
    {
        const uint* xg = reinterpret_cast<const uint*>(xv + ((long long)b * N_ + n0) * 512 + h * 64);
        uint* xls = reinterpret_cast<uint*>(xvs);
#pragma unroll
        for (int p = 0; p < 32; ++p) {
            int idx = p * 256 + t;
            int nl = idx >> 5, prt = idx & 31;
            xls[nl * 32 + prt] = xg[(long long)nl * 256 + prt];
        }
    }
    __syncthreads();
    const int l = t & 63, w = t >> 6;
    const int nlh = l >> 5, mtile = (l >> 3) & 3, dtile = l & 7;
    const int m0 = mtile * 8, d0 = dtile * 8;
    float acc[8][8] = {};
    const int wbase = w * 64;
    for (int i = 0; i < 32; ++i) {
        int nl = wbase + i * 2 + nlh;
        float4 s0 = *reinterpret_cast<const float4*>(&swsT[nl][m0]);
        float4 s1 = *reinterpret_cast<const float4*>(&swsT[nl][m0 + 4]);
        uint4 xi = *reinterpret_cast<const uint4*>(&xvs[nl * 64 + d0]);
        float xvf[8];
        xvf[0] = __uint_as_float(xi.x << 16); xvf[1] = __uint_as_float(xi.x & 0xffff0000u);
        xvf[2] = __uint_as_float(xi.y << 16); xvf[3] = __uint_as_float(xi.y & 0xffff0000u);
        xvf[4] = __uint_as_float(xi.z << 16); xvf[5] = __uint_as_float(xi.z & 0xffff0000u);
        xvf[6] = __uint_as_float(xi.w << 16); xvf[7] = __uint_as_float(xi.w & 0xffff0000u);
        float sm[8] = {s0.x, s0.y, s0.z, s0.w, s1.x, s1.y, s1.z, s1.w};
#pragma unroll
        for (int mi = 0; mi < 8; ++mi)
#pragma unroll
            for (int di = 0; di < 8; ++di)
                acc[mi][di] += sm[mi] * xvf[di];
    }
    __syncthreads();
    float* red = smem;
    float* rb = red + (w * 2 + nlh) * 2048;
#pragma unroll
    for (int mi = 0; mi < 8; ++mi) {
        float4 lo = {acc[mi][0], acc[mi][1], acc[mi][2], acc[mi][3]};
        float4 hi = {acc[mi][4], acc[mi][5], acc[mi][6], acc[mi][7]};
        *reinterpret_cast<float4*>(&rb[(m0 + mi) * 64 + d0]) = lo;
        *reinterpret_cast<float4*>(&rb[(m0 + mi) * 64 + d0 + 4]) = hi;
    }
    __syncthreads();
#pragma unroll
    for (int pp = 0; pp < 2; ++pp) {
        int idx4 = pp * 1024 + t * 4;
        float4 s = {0.f, 0.f, 0.f, 0.f};
#pragma unroll
        for (int r = 0; r < 8; ++r) {
            float4 v = *reinterpret_cast<const float4*>(&red[r * 2048 + idx4]);
            s.x += v.x; s.y += v.y; s.z += v.z; s.w += v.w;
        }
        *reinterpret_cast<float4*>(&tok_part[((long long)bh * 64 + chunk) * 2048 + idx4]) = s;
    }
}

// ---------------- K4a: sum chunks, swsum from partials, normalize, LayerNorm -> tok_ln
__global__ __launch_bounds__(64) void k4a_ln(const float* __restrict__ tok_part,
        const float* __restrict__ part, const float* __restrict__ ln_w,
        const float* __restrict__ ln_b, float* __restrict__ tok_ln) {
    const int bid = blockIdx.x;
    const int bh = bid >> 5, m = bid & 31;
    const int d = threadIdx.x;
    float s = 0.f;
    for (int ch = 0; ch < 64; ++ch)
        s += tok_part[(((long long)bh * 64 + ch) * 32 + m) * 64 + d];
    const int b = bid >> 8, c = bid & 255;
    float ssum = part[((long long)(b * 128 + d)) * 256 + c]
               + part[((long long)(b * 128 + 64 + d)) * 256 + c];
#pragma unroll
    for (int mk = 32; mk >= 1; mk >>= 1) ssum += __shfl_xor(ssum, mk, 64);
    float tokv = s / (ssum + 1e-5f);
    float mu = tokv;
#pragma unroll
    for (int mk = 32; mk >= 1; mk >>= 1) mu += __shfl_xor(mu, mk, 64);
    mu *= (1.f / 64.f);
    float df = tokv - mu;
    float var = df * df;
#pragma unroll
    for (int mk = 32; mk >= 1; mk >>= 1) var += __shfl_xor(var, mk, 64);
    var *= (1.f / 64.f);
    float y = df * rsqrtf(var + 1e-5f) * ln_w[d] + ln_b[d];
    const int bb = bh >> 3, h = bh & 7;
    tok_ln[((long long)bb * 32 + m) * 512 + h * 64 + d] = y;
}

// ---------------- wqkvT[k][j] = wqkv[j][k]
__global__ __launch_bounds__(256) void k_wqT(const float* __restrict__ wq,
        float* __restrict__ wqT) {
    __shared__ float tile[32][33];
    const int k0 = blockIdx.x * 32;
    const int j0 = blockIdx.y * 32;
    const int tx = threadIdx.x & 31, ty = threadIdx.x >> 5;
#pragma unroll
    for (int r = 0; r < 32; r += 8)
        tile[ty + r][tx] = wq[(long long)(j0 + ty + r) * 512 + k0 + tx];
    __syncthreads();
#pragma unroll
    for (int r = 0; r < 32; r += 8)
        wqT[(long long)(k0 + ty + r) * 1536 + j0 + tx] = tile[tx][ty + r];
}

// ---------------- K4b: qkv = tok_ln @ wqkv^T via transposed weights
__global__ __launch_bounds__(256) void k4b_qkv(const float* __restrict__ tok_ln,
        const float* __restrict__ wqT, float* __restrict__ qkv) {
    const int j = (blockIdx.x % 6) * 256 + threadIdx.x;
    const int r0 = (blockIdx.x / 6) * 4;
    float a0 = 0, a1 = 0, a2 = 0, a3 = 0;
    for (int k = 0; k < 512; ++k) {
        float wv = wqT[(long long)k * 1536 + j];
        a0 += tok_ln[(r0 + 0) * 512 + k] * wv;
        a1 += tok_ln[(r0 + 1) * 512 + k] * wv;
        a2 += tok_ln[(r0 + 2) * 512 + k] * wv;
        a3 += tok_ln[(r0 + 3) * 512 + k] * wv;
    }
    qkv[(long long)(r0 + 0) * 1536 + j] = a0;
    qkv[(long long)(r0 + 1) * 1536 + j] = a1;
    qkv[(long long)(r0 + 2) * 1536 + j] = a2;
    qkv[(long long)(r0 + 3) * 1536 + j] = a3;
}

// ---------------- K4c: inner MHA (M=32) per (b,h)
__global__ __launch_bounds__(256) void k4c_attn(const float* __restrict__ qkv,
        float* __restrict__ out_tok, float* __restrict__ attn_out) {
    __shared__ float qsT[64][33], ksT[64][33], vsT[64][33];
    __shared__ float att[32][33];
    __shared__ float rinv[32];
    const int t = threadIdx.x;
    const int bid = blockIdx.x;
    const int b = bid >> 3, h = bid & 7;
#pragma unroll
    for (int i = 0; i < 8; ++i) {
        int idx = i * 256 + t;
        int mi = idx >> 6, dd = idx & 63;
        long long base = ((long long)b * 32 + mi) * 1536 + h * 64 + dd;
        qsT[dd][mi] = qkv[base];
        ksT[dd][mi] = qkv[base + 512];
        vsT[dd][mi] = qkv[base + 1024];
    }
    __syncthreads();
#pragma unroll
    for (int i = 0; i < 4; ++i) {
        int idx = i * 256 + t;
        int qi = idx >> 5, ki = idx & 31;
        float s = 0.f;
#pragma unroll
        for (int dd = 0; dd < 64; ++dd) s += qsT[dd][qi] * ksT[dd][ki];
        att[qi][ki] = s * 0.125f;
    }
    __syncthreads();
    if (t < 32) {
        float mx = -1e30f;
        for (int k = 0; k < 32; ++k) mx = fmaxf(mx, att[t][k]);
        float sum = 0.f;
        for (int k = 0; k < 32; ++k) { float e = __expf(att[t][k] - mx); att[t][k] = e; sum += e; }
        rinv[t] = 1.f / sum;
    }
    __syncthreads();
#pragma unroll
    for (int i = 0; i < 4; ++i) {
        int idx = i * 256 + t;
        int qi = idx >> 5, ki = idx & 31;
        float a = att[qi][ki] * rinv[qi];
        att[qi][ki] = a;
        attn_out[(long long)bid * 1024 + qi * 32 + ki] = a;
    }
    __syncthreads();
#pragma unroll
    for (int i = 0; i < 8; ++i) {
        int idx = i * 256 + t;
        int qi = idx >> 6, dd = idx & 63;
        float s = 0.f;
#pragma unroll
        for (int ki = 0; ki < 32; ++ki) s += att[qi][ki] * vsT[dd][ki];
        out_tok[((long long)bid * 32 + qi) * 64 + dd] = s;
    }
}

// ---------------- K5: W2b[b][o][c] bf16
__global__ __launch_bounds__(256) void k5_w2(const float* __restrict__ wout,
        const float* __restrict__ out_tok, bf16* __restrict__ W2) {
    const int bid = blockIdx.x;
    const int b = bid >> 9, o = bid & 511;
    const int t = threadIdx.x;
    const int h = t >> 5, m = t & 31;
    float s = 0.f;
#pragma unroll
    for (int dd = 0; dd < 64; ++dd)
        s += wout[(long long)o * 512 + h * 64 + dd]
           * out_tok[(((long long)b * 8 + h) * 32 + m) * 64 + dd];
    W2[(long long)bid * 256 + t] = __float2bfloat16(s);
}

// ---------------- K6: out = sw_bt @ W2b^T + bout (now T2+T3+T4 core)
__global__ __launch_bounds__(256) void k6_mfma(const bf16* __restrict__ sw_bt,
        const bf16* __restrict__ W2, const float* __restrict__ bout,
        float* __restrict__ out) {
    __shared__ __align__(16) bf16 As[2][8192];
    __shared__ __align__(16) bf16 Bs[2][8192];
    f32x4 acc[4][4];
#pragma unroll
    for (int i = 0; i < 4; ++i)
#pragma unroll
        for (int j = 0; j < 4; ++j) acc[i][j] = (f32x4)(0.0f);
    const int wg = xcd_swz((blockIdx.z * 128 + blockIdx.y) * 4 + blockIdx.x, 2048);
    const int bx = wg & 3, by = (wg >> 2) & 127, bz = wg >> 9;
    const long long arow0 = (long long)by * 128;
    const int bcol0 = bx * 128;
    gemm_cnt<4>(sw_bt + (long long)bz * N_ * 256, W2 + (long long)bz * 512 * 256,
                arow0, bcol0, 256, 256, As, Bs, acc);
    const int l = threadIdx.x & 63, w = threadIdx.x >> 6;
    const int wm = w >> 1, wn = w & 1;
#pragma unroll
    for (int mf = 0; mf < 4; ++mf) {
#pragma unroll
        for (int nf = 0; nf < 4; ++nf) {
            int col = bcol0 + wn * 64 + nf * 16 + (l & 15);
            float bv = bout[col];
#pragma unroll
            for (int r = 0; r < 4; ++r) {
                long long row = arow0 + wm * 64 + mf * 16 + (l >> 4) * 4 + r;
                out[((long long)bz * N_ + row) * 512 + col] = acc[mf][nf][r] + bv;
            }
        }
    }
}

// ---------------- misc outputs
__global__ void k_misc(const float* __restrict__ alpha1,
        float* __restrict__ outA, float* __restrict__ outZ) {
    int t = threadIdx.x;
    if (t < 8) outA[t] = alpha1[t];
    outZ[t] = 0.f;
}

extern "C" void kernel_launch(void* const* d_in, const int* in_sizes, int n_in,
                              void* d_out, int out_size, void* d_ws, size_t ws_size,
                              hipStream_t stream) {
    const float* x      = (const float*)d_in[0];
    const float* wkv    = (const float*)d_in[1];
    const float* bkv    = (const float*)d_in[2];
    const float* wtq    = (const float*)d_in[3];
    const float* alpha1 = (const float*)d_in[4];
    const float* mix1_w = (const float*)d_in[5];
    const float* ln1_w  = (const float*)d_in[6];
    const float* ln1_b  = (const float*)d_in[7];
    const float* wqkv   = (const float*)d_in[8];
    const float* wout   = (const float*)d_in[9];
    const float* bout   = (const float*)d_in[10];

    float* out    = (float*)d_out;
    float* swout  = out + 33554432LL;
    float* alphaO = out + 50331648LL;
    float* zerosO = out + 50331656LL;
    float* attnO  = out + 50331912LL;

    char* ws = (char*)d_ws;
    bf16*  xb        = (bf16*)(ws);                      // 64 MiB [cast -> k12]
    float* wqkvT     = (float*)(ws);                     // 3 MiB  [wqT -> k4b] (over dead xb)
    float* wf_f32    = (float*)(ws + 35651584LL);        // 512 KiB [wfused -> wsc] (over xb, dead before x-cast)
    float* part      = (float*)(ws + 67108864LL);        // 512 KiB [k12 -> k4a]
    bf16*  sw_bt     = (bf16*)(ws + 100663296LL);        // 32 MiB [k12 -> k3,k6]
    bf16*  xv        = (bf16*)(ws + 134217728LL);        // 64 MiB [k12 -> k3]
    float* tok_part  = (float*)(ws + 201326592LL);       // 16 MiB [k3 -> k4a]
    float* tok_ln    = (float*)(ws + 218107904LL);       // 256 KiB
    float* qkv       = (float*)(ws + 218370048LL);       // 768 KiB
    float* out_tok   = (float*)(ws + 219156480LL);       // 256 KiB
    bf16*  W2b       = (bf16*)(ws + 219418624LL);        // 1 MiB
    bf16*  wv_sc     = (bf16*)(ws + 220467200LL);        // 768 KiB [768][512]
    float* bias768   = (float*)(ws + 221253632LL);       // 3 KiB

    // prep: weights (wf_f32 lives inside xb region, dead before x-cast)
    k_cast4<<<256, 256, 0, stream>>>(wkv + 262144, (ushort*)wv_sc);   // v-half -> rows 0..511
    k_wfused<<<512, 256, 0, stream>>>(mix1_w, wtq, wf_f32);
    k_wsc<<<256, 256, 0, stream>>>(wf_f32, wkv, bkv, alpha1, wv_sc, bias768);
    k_cast4<<<32768, 256, 0, stream>>>(x, (ushort*)xb);
    // main pipeline
    k12_mfma<<<dim3(6, 512), 256, 0, stream>>>(xb, wv_sc, bias768, xv, swout, sw_bt, part);
    k_wqT<<<dim3(16, 48), 256, 0, stream>>>(wqkv, wqkvT);
    k3_tok<<<dim3(64, 32), 256, 0, stream>>>(sw_bt, xv, tok_part);
    k4a_ln<<<1024, 64, 0, stream>>>(tok_part, part, ln1_w, ln1_b, tok_ln);
    k4b_qkv<<<192, 256, 0, stream>>>(tok_ln, wqkvT, qkv);
    k4c_attn<<<32, 256, 0, stream>>>(qkv, out_tok, attnO);
    k5_w2<<<2048, 256, 0, stream>>>(wout, out_tok, W2b);
    k6_mfma<<<dim3(4, 128, 4), 256, 0, stream>>>(sw_bt, W2b, bout, out);
    k_misc<<<1, 256, 0, stream>>>(alpha1, alphaO, zerosO);
}

// Round 15
// 328.380 us; speedup vs baseline: 1.0698x; 1.0188x over previous
//
#include <hip/hip_runtime.h>
#include <hip/hip_bf16.h>

#define B_ 4
#define N_ 16384
#define HID_ 512
#define H_ 8
#define M_ 32
#define D_ 64
#define HM_ 256

typedef __hip_bfloat16 bf16;
typedef __bf16 bf16x8 __attribute__((ext_vector_type(8)));
typedef float f32x4 __attribute__((ext_vector_type(4)));

__device__ __forceinline__ void gl_lds16(const bf16* g, bf16* l) {
    __builtin_amdgcn_global_load_lds(
        (const __attribute__((address_space(1))) void*)g,
        (__attribute__((address_space(3))) void*)l, 16, 0, 0);
}

// XCD-aware bijective block remap (requires nwg % 8 == 0)
__device__ __forceinline__ int xcd_swz(int lin, int nwg) {
    return (lin & 7) * (nwg >> 3) + (lin >> 3);
}

// ---- T2 swizzled stage: global col-block (l&7)^srow -> linear LDS slot l&7.
__device__ __forceinline__ void stage_tile_sw(const bf16* __restrict__ G, long long r0,
        int kk, int ld, bf16* lds, int t) {
    const int l = t & 63, w = t >> 6;
    const int srow = l >> 3;
    const int skel = ((l & 7) ^ srow) * 8;   // pre-swizzled source col block
#pragma unroll
    for (int j = 0; j < 4; ++j) {
        int q = j * 4 + w;
        gl_lds16(G + (r0 + q * 8 + srow) * (long long)ld + kk + skel, lds + q * 512);
    }
}

// ---- one 64-K-step of MFMA on XOR-swizzled LDS tiles; T5 setprio around cluster
__device__ __forceinline__ void mfma_half_sw(const bf16* As, const bf16* Bs,
        int l, int wm, int wn, f32x4 acc[4][4]) {
    const int l15 = l & 15;
    const int xsw = (l & 7) * 8;
    const int kq = (l >> 4) * 8;
    __builtin_amdgcn_s_setprio(1);
#pragma unroll
    for (int ks = 0; ks < 64; ks += 32) {
        const int ko = (ks + kq) ^ xsw;
        bf16x8 af[4], bfr[4];
#pragma unroll
        for (int mf = 0; mf < 4; ++mf)
            af[mf] = *(const bf16x8*)(As + (wm * 64 + mf * 16 + l15) * 64 + ko);
#pragma unroll
        for (int nf = 0; nf < 4; ++nf)
            bfr[nf] = *(const bf16x8*)(Bs + (wn * 64 + nf * 16 + l15) * 64 + ko);
#pragma unroll
        for (int mf = 0; mf < 4; ++mf)
#pragma unroll
            for (int nf = 0; nf < 4; ++nf)
                acc[mf][nf] = __builtin_amdgcn_mfma_f32_16x16x32_bf16(af[mf], bfr[nf], acc[mf][nf], 0, 0, 0);
    }
    __builtin_amdgcn_s_setprio(0);
}

// ---- T2+T3+T4 2-phase core: counted vmcnt keeps the kt+1 prefetch (8 loads/thread)
// in flight across the barrier; tiles XOR-swizzled for conflict-free ds_read.
template<int NT>
__device__ __forceinline__ void gemm_cnt(
        const bf16* __restrict__ Ag, const bf16* __restrict__ Bg,
        long long arow0, int bcol0, int lda, int ldb,
        bf16 (*As)[8192], bf16 (*Bs)[8192], f32x4 acc[4][4]) {
    const int t = threadIdx.x;
    const int l = t & 63, w = t >> 6;
    const int wm = w >> 1, wn = w & 1;
    stage_tile_sw(Ag, arow0, 0, lda, As[0], t);
    stage_tile_sw(Bg, bcol0, 0, ldb, Bs[0], t);
#pragma unroll
    for (int kt = 0; kt < NT; ++kt) {
        const int cur = kt & 1;
        if (kt + 1 < NT) {
            stage_tile_sw(Ag, arow0, (kt + 1) * 64, lda, As[cur ^ 1], t);
            stage_tile_sw(Bg, bcol0, (kt + 1) * 64, ldb, Bs[cur ^ 1], t);
            asm volatile("s_waitcnt vmcnt(8)" ::: "memory");   // tile kt done; kt+1 flying
        } else {
            asm volatile("s_waitcnt vmcnt(0)" ::: "memory");
        }
        __builtin_amdgcn_s_barrier();       // staging visible to all waves
        mfma_half_sw(As[cur], Bs[cur], l, wm, wn, acc);
        __builtin_amdgcn_s_barrier();       // all reads done before buf reuse next iter
    }
}

// ---------------- cast f32 -> bf16, 4 elems/thread (x only)
__global__ __launch_bounds__(256) void k_cast4(const float* __restrict__ s,
        ushort* __restrict__ d) {
    long long i = (long long)blockIdx.x * 256 + threadIdx.x;
    float4 v = reinterpret_cast<const float4*>(s)[i];
    ushort4 o;
    bf16 a0 = __float2bfloat16(v.x), a1 = __float2bfloat16(v.y);
    bf16 a2 = __float2bfloat16(v.z), a3 = __float2bfloat16(v.w);
    o.x = *(ushort*)&a0; o.y = *(ushort*)&a1; o.z = *(ushort*)&a2; o.w = *(ushort*)&a3;
    reinterpret_cast<ushort4*>(d)[i] = o;
}

// ---------------- k_prep: fused weight prep. Per block o (256 blocks):
//  wfrow[k] = sum_m mix1[o, h*32+m]*wtq[h,m,d]  (in LDS, no HBM round-trip)
//  wv_sc rows 512+o = bf16(alpha * wfrow @ wkv_k); bias768[512+o] = alpha * wfrow.bkv_k
//  wv_sc rows 2o,2o+1 = bf16(wkv v-half); bias768[2o..2o+1] = bkv v-half
__global__ __launch_bounds__(256) void k_prep(const float* __restrict__ mix1,
        const float* __restrict__ wtq, const float* __restrict__ wkv,
        const float* __restrict__ bkv, const float* __restrict__ alpha1,
        bf16* __restrict__ wv_sc, float* __restrict__ bias768) {
    __shared__ float wfrow[512];
    __shared__ float red[256];
    const int o = blockIdx.x, t = threadIdx.x;
#pragma unroll
    for (int half = 0; half < 2; ++half) {
        int k = half * 256 + t;
        int h = k >> 6, dd = k & 63;
        float s = 0.f;
#pragma unroll
        for (int m = 0; m < 32; ++m)
            s += mix1[(long long)o * 256 + h * 32 + m] * wtq[((long long)h * 32 + m) * 64 + dd];
        wfrow[k] = s;
    }
    __syncthreads();
    const float al = alpha1[o >> 5];
    float a0 = 0.f, a1 = 0.f;
    for (int c = 0; c < 512; ++c) {
        float wv = wfrow[c];
        a0 += wv * wkv[(long long)c * 512 + t];
        a1 += wv * wkv[(long long)c * 512 + t + 256];
    }
    wv_sc[(long long)(512 + o) * 512 + t] = __float2bfloat16(a0 * al);
    wv_sc[(long long)(512 + o) * 512 + t + 256] = __float2bfloat16(a1 * al);
    float p = wfrow[t] * bkv[t] + wfrow[t + 256] * bkv[t + 256];
    red[t] = p; __syncthreads();
    for (int s = 128; s >= 1; s >>= 1) {
        if (t < s) red[t] += red[t + s];
        __syncthreads();
    }
    if (t == 0) bias768[512 + o] = red[0] * al;
    if (t < 2) bias768[o * 2 + t] = bkv[512 + o * 2 + t];   // v-bias
    // v-half cast: rows 2o, 2o+1
#pragma unroll
    for (int j = 0; j < 4; ++j) {
        int idx = j * 256 + t;                 // 0..1023
        int r = 2 * o + (idx >> 9), col = idx & 511;
        wv_sc[(long long)r * 512 + col]
            = __float2bfloat16(wkv[(long long)(512 + r) * 512 + col]);
    }
}

// ---------------- K12: [xv | scores] = xb @ wv_sc^T + bias768; counted-vmcnt 2-phase
// with T2 swizzle; score blocks run the m-group softmax in-register; direct stores.
__global__ __launch_bounds__(256) void k12_mfma(const bf16* __restrict__ xb,
        const bf16* __restrict__ wv_sc, const float* __restrict__ bias768,
        bf16* __restrict__ xv, float* __restrict__ swout,
        bf16* __restrict__ sw_bt, float* __restrict__ part) {
    __shared__ __align__(16) bf16 As[2][8192];
    __shared__ __align__(16) bf16 Bs[2][8192];
    f32x4 acc[4][4];
#pragma unroll
    for (int i = 0; i < 4; ++i)
#pragma unroll
        for (int j = 0; j < 4; ++j) acc[i][j] = (f32x4)(0.0f);
    const int wg = xcd_swz(blockIdx.y * 6 + blockIdx.x, 3072);
    const int bx = wg % 6, by = wg / 6;
    const long long arow0 = (long long)by * 128;
    const int bcol0 = bx * 128;
    gemm_cnt<8>(xb, wv_sc, arow0, bcol0, 512, 512, As, Bs, acc);

    const int t = threadIdx.x;
    const int l = t & 63, w = t >> 6, wm = w >> 1, wn = w & 1;
    const int l15 = l & 15, lq = l >> 4;
    // add bias
#pragma unroll
    for (int nf = 0; nf < 4; ++nf) {
        float bv = bias768[bcol0 + wn * 64 + nf * 16 + l15];
#pragma unroll
        for (int mf = 0; mf < 4; ++mf)
#pragma unroll
            for (int r = 0; r < 4; ++r) acc[mf][nf][r] += bv;
    }

    if (bcol0 >= 512) {
        // ---- in-register softmax over each m-group (32 cols = nf pair x 16 lanes)
#pragma unroll
        for (int mf = 0; mf < 4; ++mf)
#pragma unroll
            for (int r = 0; r < 4; ++r)
#pragma unroll
                for (int g = 0; g < 2; ++g) {
                    float v0 = acc[mf][2 * g][r], v1 = acc[mf][2 * g + 1][r];
                    float mx = fmaxf(v0, v1);
#pragma unroll
                    for (int mk = 1; mk <= 8; mk <<= 1) mx = fmaxf(mx, __shfl_xor(mx, mk));
                    float e0 = __expf(v0 - mx), e1 = __expf(v1 - mx);
                    float s = e0 + e1;
#pragma unroll
                    for (int mk = 1; mk <= 8; mk <<= 1) s += __shfl_xor(s, mk);
                    float ri = 1.f / s;
                    acc[mf][2 * g][r] = e0 * ri;
                    acc[mf][2 * g + 1][r] = e1 * ri;
                }
        // ---- per-column partial sums (for swsum)
        {
            float* cpart = (float*)&As[0][0];   // 256 floats
#pragma unroll
            for (int nf = 0; nf < 4; ++nf) {
                float ps = 0.f;
#pragma unroll
                for (int mf = 0; mf < 4; ++mf)
#pragma unroll
                    for (int r = 0; r < 4; ++r) ps += acc[mf][nf][r];
                ps += __shfl_xor(ps, 16);
                ps += __shfl_xor(ps, 32);
                if (lq == 0) cpart[wm * 128 + wn * 64 + nf * 16 + l15] = ps;
            }
            __syncthreads();
            if (t < 128)
                part[(long long)by * 256 + (bcol0 - 512) + t] = cpart[t] + cpart[128 + t];
        }
        // ---- direct register stores
        const int b = (int)(arow0 >> 14);
        const int nbase = (int)(arow0 & 16383) + wm * 64;
#pragma unroll
        for (int mf = 0; mf < 4; ++mf) {
            long long rowb = arow0 + wm * 64 + mf * 16 + lq * 4;
#pragma unroll
            for (int nf = 0; nf < 4; ++nf) {
                int cglob = (bcol0 - 512) + wn * 64 + nf * 16 + l15;
                float4 v = {acc[mf][nf][0], acc[mf][nf][1], acc[mf][nf][2], acc[mf][nf][3]};
                *reinterpret_cast<float4*>(swout + ((long long)b * HM_ + cglob) * N_
                                           + nbase + mf * 16 + lq * 4) = v;
#pragma unroll
                for (int r = 0; r < 4; ++r)
                    sw_bt[(rowb + r) * 256 + cglob] = __float2bfloat16(acc[mf][nf][r]);
            }
        }
    } else {
        // ---- xv path: direct scalar bf16 stores
#pragma unroll
        for (int mf = 0; mf < 4; ++mf) {
            long long rowb = arow0 + wm * 64 + mf * 16 + lq * 4;
#pragma unroll
            for (int nf = 0; nf < 4; ++nf) {
                int col = bcol0 + wn * 64 + nf * 16 + l15;
#pragma unroll
                for (int r = 0; r < 4; ++r)
                    xv[(rowb + r) * 512 + col] = __float2bfloat16(acc[mf][nf][r]);
            }
        }
    }
}

// ---------------- K3: register-tiled outer-product over 512 n per block (2 passes):
// tok_part[bh][chunk32][m][d]
__global__ __launch_bounds__(256) void k3_tok(const bf16* __restrict__ sw_bt,
        const bf16* __restrict__ xv, float* __restrict__ tok_part) {
    __shared__ __align__(16) float smem[17408];
    float (*swsT)[36] = reinterpret_cast<float(*)[36]>(smem);
    bf16* xvs = reinterpret_cast<bf16*>(smem + 9216);
    const int t = threadIdx.x;
    const int chunk = blockIdx.x;   // 0..31, 512 n each
    const int bh = blockIdx.y;
    const int b = bh >> 3, h = bh & 7;
    const int l = t & 63, w = t >> 6;
    const int nlh = l >> 5, mtile = (l >> 3) & 3, dtile = l & 7;
    const int m0 = mtile * 8, d0 = dtile * 8;
    float acc[8][8] = {};
    const int wbase = w * 64;

    for (int pass = 0; pass < 2; ++pass) {
        const int n0 = chunk * 512 + pass * 256;
        // stage sw (bf16 [row][c]) transposed to [nl][m]
        {
            const long long base = ((long long)(b * N_ + n0 + t)) * 256 + h * 32;
            const uint4* sp = reinterpret_cast<const uint4*>(sw_bt + base);
            uint4 qs[4] = {sp[0], sp[1], sp[2], sp[3]};
            const uint* qu = reinterpret_cast<const uint*>(qs);
#pragma unroll
            for (int j = 0; j < 16; ++j) {
                uint u = qu[j];
                swsT[t][2 * j] = __uint_as_float(u << 16);
                swsT[t][2 * j + 1] = __uint_as_float(u & 0xffff0000u);
            }
        }
        {
            const uint* xg = reinterpret_cast<const uint*>(xv + ((long long)b * N_ + n0) * 512 + h * 64);
            uint* xls = reinterpret_cast<uint*>(xvs);
#pragma unroll
            for (int p = 0; p < 32; ++p) {
                int idx = p * 256 + t;
                int nl = idx >> 5, prt = idx & 31;
                xls[nl * 32 + prt] = xg[(long long)nl * 256 + prt];
            }
        }
        __syncthreads();
        for (int i = 0; i < 32; ++i) {
            int nl = wbase + i * 2 + nlh;
            float4 s0 = *reinterpret_cast<const float4*>(&swsT[nl][m0]);
            float4 s1 = *reinterpret_cast<const float4*>(&swsT[nl][m0 + 4]);
            uint4 xi = *reinterpret_cast<const uint4*>(&xvs[nl * 64 + d0]);
            float xvf[8];
            xvf[0] = __uint_as_float(xi.x << 16); xvf[1] = __uint_as_float(xi.x & 0xffff0000u);
            xvf[2] = __uint_as_float(xi.y << 16); xvf[3] = __uint_as_float(xi.y & 0xffff0000u);
            xvf[4] = __uint_as_float(xi.z << 16); xvf[5] = __uint_as_float(xi.z & 0xffff0000u);
            xvf[6] = __uint_as_float(xi.w << 16); xvf[7] = __uint_as_float(xi.w & 0xffff0000u);
            float sm[8] = {s0.x, s0.y, s0.z, s0.w, s1.x, s1.y, s1.z, s1.w};
#pragma unroll
            for (int mi = 0; mi < 8; ++mi)
#pragma unroll
                for (int di = 0; di < 8; ++di)
                    acc[mi][di] += sm[mi] * xvf[di];
        }
        __syncthreads();   // all reads done before next pass / reduce reuses smem
    }

    float* red = smem;
    float* rb = red + (w * 2 + nlh) * 2048;
#pragma unroll
    for (int mi = 0; mi < 8; ++mi) {
        float4 lo = {acc[mi][0], acc[mi][1], acc[mi][2], acc[mi][3]};
        float4 hi = {acc[mi][4], acc[mi][5], acc[mi][6], acc[mi][7]};
        *reinterpret_cast<float4*>(&rb[(m0 + mi) * 64 + d0]) = lo;
        *reinterpret_cast<float4*>(&rb[(m0 + mi) * 64 + d0 + 4]) = hi;
    }
    __syncthreads();
#pragma unroll
    for (int pp = 0; pp < 2; ++pp) {
        int idx4 = pp * 1024 + t * 4;
        float4 s = {0.f, 0.f, 0.f, 0.f};
#pragma unroll
        for (int r = 0; r < 8; ++r) {
            float4 v = *reinterpret_cast<const float4*>(&red[r * 2048 + idx4]);
            s.x += v.x; s.y += v.y; s.z += v.z; s.w += v.w;
        }
        *reinterpret_cast<float4*>(&tok_part[((long long)bh * 32 + chunk) * 2048 + idx4]) = s;
    }
}

// ---------------- K4a: sum 32 chunks, swsum from partials, normalize, LN -> tok_ln
__global__ __launch_bounds__(64) void k4a_ln(const float* __restrict__ tok_part,
        const float* __restrict__ part, const float* __restrict__ ln_w,
        const float* __restrict__ ln_b, float* __restrict__ tok_ln) {
    const int bid = blockIdx.x;
    const int bh = bid >> 5, m = bid & 31;
    const int d = threadIdx.x;
    float s = 0.f;
    for (int ch = 0; ch < 32; ++ch)
        s += tok_part[(((long long)bh * 32 + ch) * 32 + m) * 64 + d];
    const int b = bid >> 8, c = bid & 255;
    float ssum = part[((long long)(b * 128 + d)) * 256 + c]
               + part[((long long)(b * 128 + 64 + d)) * 256 + c];
#pragma unroll
    for (int mk = 32; mk >= 1; mk >>= 1) ssum += __shfl_xor(ssum, mk, 64);
    float tokv = s / (ssum + 1e-5f);
    float mu = tokv;
#pragma unroll
    for (int mk = 32; mk >= 1; mk >>= 1) mu += __shfl_xor(mu, mk, 64);
    mu *= (1.f / 64.f);
    float df = tokv - mu;
    float var = df * df;
#pragma unroll
    for (int mk = 32; mk >= 1; mk >>= 1) var += __shfl_xor(var, mk, 64);
    var *= (1.f / 64.f);
    float y = df * rsqrtf(var + 1e-5f) * ln_w[d] + ln_b[d];
    const int bb = bh >> 3, h = bh & 7;
    tok_ln[((long long)bb * 32 + m) * 512 + h * 64 + d] = y;
}

// ---------------- wqkvT[k][j] = wqkv[j][k]
__global__ __launch_bounds__(256) void k_wqT(const float* __restrict__ wq,
        float* __restrict__ wqT) {
    __shared__ float tile[32][33];
    const int k0 = blockIdx.x * 32;
    const int j0 = blockIdx.y * 32;
    const int tx = threadIdx.x & 31, ty = threadIdx.x >> 5;
#pragma unroll
    for (int r = 0; r < 32; r += 8)
        tile[ty + r][tx] = wq[(long long)(j0 + ty + r) * 512 + k0 + tx];
    __syncthreads();
#pragma unroll
    for (int r = 0; r < 32; r += 8)
        wqT[(long long)(k0 + ty + r) * 1536 + j0 + tx] = tile[tx][ty + r];
}

// ---------------- K4b: qkv = tok_ln @ wqkv^T via transposed weights
__global__ __launch_bounds__(256) void k4b_qkv(const float* __restrict__ tok_ln,
        const float* __restrict__ wqT, float* __restrict__ qkv) {
    const int j = (blockIdx.x % 6) * 256 + threadIdx.x;
    const int r0 = (blockIdx.x / 6) * 4;
    float a0 = 0, a1 = 0, a2 = 0, a3 = 0;
    for (int k = 0; k < 512; ++k) {
        float wv = wqT[(long long)k * 1536 + j];
        a0 += tok_ln[(r0 + 0) * 512 + k] * wv;
        a1 += tok_ln[(r0 + 1) * 512 + k] * wv;
        a2 += tok_ln[(r0 + 2) * 512 + k] * wv;
        a3 += tok_ln[(r0 + 3) * 512 + k] * wv;
    }
    qkv[(long long)(r0 + 0) * 1536 + j] = a0;
    qkv[(long long)(r0 + 1) * 1536 + j] = a1;
    qkv[(long long)(r0 + 2) * 1536 + j] = a2;
    qkv[(long long)(r0 + 3) * 1536 + j] = a3;
}

// ---------------- K4c: inner MHA (M=32) per (b,h)
__global__ __launch_bounds__(256) void k4c_attn(const float* __restrict__ qkv,
        float* __restrict__ out_tok, float* __restrict__ attn_out) {
    __shared__ float qsT[64][33], ksT[64][33], vsT[64][33];
    __shared__ float att[32][33];
    __shared__ float rinv[32];
    const int t = threadIdx.x;
    const int bid = blockIdx.x;
    const int b = bid >> 3, h = bid & 7;
#pragma unroll
    for (int i = 0; i < 8; ++i) {
        int idx = i * 256 + t;
        int mi = idx >> 6, dd = idx & 63;
        long long base = ((long long)b * 32 + mi) * 1536 + h * 64 + dd;
        qsT[dd][mi] = qkv[base];
        ksT[dd][mi] = qkv[base + 512];
        vsT[dd][mi] = qkv[base + 1024];
    }
    __syncthreads();
#pragma unroll
    for (int i = 0; i < 4; ++i) {
        int idx = i * 256 + t;
        int qi = idx >> 5, ki = idx & 31;
        float s = 0.f;
#pragma unroll
        for (int dd = 0; dd < 64; ++dd) s += qsT[dd][qi] * ksT[dd][ki];
        att[qi][ki] = s * 0.125f;
    }
    __syncthreads();
    if (t < 32) {
        float mx = -1e30f;
        for (int k = 0; k < 32; ++k) mx = fmaxf(mx, att[t][k]);
        float sum = 0.f;
        for (int k = 0; k < 32; ++k) { float e = __expf(att[t][k] - mx); att[t][k] = e; sum += e; }
        rinv[t] = 1.f / sum;
    }
    __syncthreads();
#pragma unroll
    for (int i = 0; i < 4; ++i) {
        int idx = i * 256 + t;
        int qi = idx >> 5, ki = idx & 31;
        float a = att[qi][ki] * rinv[qi];
        att[qi][ki] = a;
        attn_out[(long long)bid * 1024 + qi * 32 + ki] = a;
    }
    __syncthreads();
#pragma unroll
    for (int i = 0; i < 8; ++i) {
        int idx = i * 256 + t;
        int qi = idx >> 6, dd = idx & 63;
        float s = 0.f;
#pragma unroll
        for (int ki = 0; ki < 32; ++ki) s += att[qi][ki] * vsT[dd][ki];
        out_tok[((long long)bid * 32 + qi) * 64 + dd] = s;
    }
}

// ---------------- K5: W2b[b][o][c] bf16
__global__ __launch_bounds__(256) void k5_w2(const float* __restrict__ wout,
        const float* __restrict__ out_tok, bf16* __restrict__ W2) {
    const int bid = blockIdx.x;
    const int b = bid >> 9, o = bid & 511;
    const int t = threadIdx.x;
    const int h = t >> 5, m = t & 31;
    float s = 0.f;
#pragma unroll
    for (int dd = 0; dd < 64; ++dd)
        s += wout[(long long)o * 512 + h * 64 + dd]
           * out_tok[(((long long)b * 8 + h) * 32 + m) * 64 + dd];
    W2[(long long)bid * 256 + t] = __float2bfloat16(s);
}

// ---------------- K6: out = sw_bt @ W2b^T + bout (T2+T3+T4 core)
__global__ __launch_bounds__(256) void k6_mfma(const bf16* __restrict__ sw_bt,
        const bf16* __restrict__ W2, const float* __restrict__ bout,
        float* __restrict__ out) {
    __shared__ __align__(16) bf16 As[2][8192];
    __shared__ __align__(16) bf16 Bs[2][8192];
    f32x4 acc[4][4];
#pragma unroll
    for (int i = 0; i < 4; ++i)
#pragma unroll
        for (int j = 0; j < 4; ++j) acc[i][j] = (f32x4)(0.0f);
    const int wg = xcd_swz((blockIdx.z * 128 + blockIdx.y) * 4 + blockIdx.x, 2048);
    const int bx = wg & 3, by = (wg >> 2) & 127, bz = wg >> 9;
    const long long arow0 = (long long)by * 128;
    const int bcol0 = bx * 128;
    gemm_cnt<4>(sw_bt + (long long)bz * N_ * 256, W2 + (long long)bz * 512 * 256,
                arow0, bcol0, 256, 256, As, Bs, acc);
    const int l = threadIdx.x & 63, w = threadIdx.x >> 6;
    const int wm = w >> 1, wn = w & 1;
#pragma unroll
    for (int mf = 0; mf < 4; ++mf) {
#pragma unroll
        for (int nf = 0; nf < 4; ++nf) {
            int col = bcol0 + wn * 64 + nf * 16 + (l & 15);
            float bv = bout[col];
#pragma unroll
            for (int r = 0; r < 4; ++r) {
                long long row = arow0 + wm * 64 + mf * 16 + (l >> 4) * 4 + r;
                out[((long long)bz * N_ + row) * 512 + col] = acc[mf][nf][r] + bv;
            }
        }
    }
}

// ---------------- misc outputs
__global__ void k_misc(const float* __restrict__ alpha1,
        float* __restrict__ outA, float* __restrict__ outZ) {
    int t = threadIdx.x;
    if (t < 8) outA[t] = alpha1[t];
    outZ[t] = 0.f;
}

extern "C" void kernel_launch(void* const* d_in, const int* in_sizes, int n_in,
                              void* d_out, int out_size, void* d_ws, size_t ws_size,
                              hipStream_t stream) {
    const float* x      = (const float*)d_in[0];
    const float* wkv    = (const float*)d_in[1];
    const float* bkv    = (const float*)d_in[2];
    const float* wtq    = (const float*)d_in[3];
    const float* alpha1 = (const float*)d_in[4];
    const float* mix1_w = (const float*)d_in[5];
    const float* ln1_w  = (const float*)d_in[6];
    const float* ln1_b  = (const float*)d_in[7];
    const float* wqkv   = (const float*)d_in[8];
    const float* wout   = (const float*)d_in[9];
    const float* bout   = (const float*)d_in[10];

    float* out    = (float*)d_out;
    float* swout  = out + 33554432LL;
    float* alphaO = out + 50331648LL;
    float* zerosO = out + 50331656LL;
    float* attnO  = out + 50331912LL;

    char* ws = (char*)d_ws;
    bf16*  xb        = (bf16*)(ws);                      // 64 MiB [cast -> k12]
    float* wqkvT     = (float*)(ws);                     // 3 MiB  [wqT -> k4b] (over dead xb)
    float* part      = (float*)(ws + 67108864LL);        // 512 KiB [k12 -> k4a]
    bf16*  sw_bt     = (bf16*)(ws + 100663296LL);        // 32 MiB [k12 -> k3,k6]
    bf16*  xv        = (bf16*)(ws + 134217728LL);        // 64 MiB [k12 -> k3]
    float* tok_part  = (float*)(ws + 201326592LL);       // 8 MiB [k3 -> k4a]
    float* tok_ln    = (float*)(ws + 218107904LL);       // 256 KiB
    float* qkv       = (float*)(ws + 218370048LL);       // 768 KiB
    float* out_tok   = (float*)(ws + 219156480LL);       // 256 KiB
    bf16*  W2b       = (bf16*)(ws + 219418624LL);        // 1 MiB
    bf16*  wv_sc     = (bf16*)(ws + 220467200LL);        // 768 KiB [768][512]
    float* bias768   = (float*)(ws + 221253632LL);       // 3 KiB

    // prep
    k_prep<<<256, 256, 0, stream>>>(mix1_w, wtq, wkv, bkv, alpha1, wv_sc, bias768);
    k_cast4<<<32768, 256, 0, stream>>>(x, (ushort*)xb);
    // main pipeline
    k12_mfma<<<dim3(6, 512), 256, 0, stream>>>(xb, wv_sc, bias768, xv, swout, sw_bt, part);
    k_wqT<<<dim3(16, 48), 256, 0, stream>>>(wqkv, wqkvT);
    k3_tok<<<dim3(32, 32), 256, 0, stream>>>(sw_bt, xv, tok_part);
    k4a_ln<<<1024, 64, 0, stream>>>(tok_part, part, ln1_w, ln1_b, tok_ln);
    k4b_qkv<<<192, 256, 0, stream>>>(tok_ln, wqkvT, qkv);
    k4c_attn<<<32, 256, 0, stream>>>(qkv, out_tok, attnO);
    k5_w2<<<2048, 256, 0, stream>>>(wout, out_tok, W2b);
    k6_mfma<<<dim3(4, 128, 4), 256, 0, stream>>>(sw_bt, W2b, bout, out);
    k_misc<<<1, 256, 0, stream>>>(alpha1, alphaO, zerosO);
}